// Round 9
// baseline (513.269 us; speedup 1.0000x reference)
//
#include <hip/hip_runtime.h>

typedef __attribute__((ext_vector_type(8))) short short8;
typedef __attribute__((ext_vector_type(4))) float f32x4;

#define N_NODES 1000000
#define N_UPD   200000
#define D       172
#define BM      64          // rows per GRU block
#define LDA     360         // LDS A row stride in ushorts
#define KSTEPS  11          // 11 * 32 = 352 >= 344
#define NTILES  48
#define KSLICE  (NTILES*512)
#define GRU_BLOCKS (N_UPD / BM)              // 3125
#define NCYC    131                          // cycles of 5 groups (3 gru : 2 copy)
#define NCOPY_BLOCKS (NCYC*2*8)              // 2096
#define COPY_STRIDE (NCOPY_BLOCKS*512)       // 1073152
#define NM4 43000000
#define BPACK_USHORTS (KSTEPS*KSLICE)        // 270336
#define BIAS_OFF  (BPACK_USHORTS*2)          // 540672 B
#define MASK_OFF  (BIAS_OFF + 688*4)         // 543424 B
#define WS_NEED   (MASK_OFF + N_NODES)

__device__ __forceinline__ unsigned short f2bf(float f) {
  union { float f; unsigned u; } v; v.f = f;
  unsigned r = v.u + 0x7FFFu + ((v.u >> 16) & 1u);
  return (unsigned short)(r >> 16);
}
__device__ __forceinline__ float bf2f(unsigned short h) {
  union { unsigned u; float f; } v; v.u = ((unsigned)h) << 16;
  return v.f;
}
__device__ __forceinline__ ushort4 f2bf4(float4 v) {
  return make_ushort4(f2bf(v.x), f2bf(v.y), f2bf(v.z), f2bf(v.w));
}

// ---------------------------------------------------------------------------
// Prep: pack B into MFMA-fragment order + fused biases + clear node mask.
// Bpack[((ks*48+nt)*64+lane)*8+e] = B[ks*32+(lane>>4)*8+e][nt*16+(lane&15)]
// nt = wc*12 + gate*3 + ti ; col j = wc*48 + ti*16 + (lane&15).
// ---------------------------------------------------------------------------
__global__ void prep_kernel(const float* __restrict__ wih, const float* __restrict__ whh,
                            const float* __restrict__ bih, const float* __restrict__ bhh,
                            unsigned short* __restrict__ Bpack, float* __restrict__ bias4,
                            uint4* __restrict__ mask16) {
  int gid = blockIdx.x * 256 + threadIdx.x;
  if (gid < 688) {
    int which = gid / 172, j = gid % 172;
    float v;
    if (which == 0)      v = bih[j]       + bhh[j];
    else if (which == 1) v = bih[172 + j] + bhh[172 + j];
    else if (which == 2) v = bih[344 + j];
    else                 v = bhh[344 + j];
    bias4[gid] = v;
  }
  if (gid < N_NODES / 16) mask16[gid] = make_uint4(0, 0, 0, 0);
  if (gid >= BPACK_USHORTS) return;
  int e  = gid & 7;
  int l  = (gid >> 3) & 63;
  int nt = (gid >> 9) % NTILES;
  int ks = gid / KSLICE;
  int k  = ks * 32 + ((l >> 4) << 3) + e;
  int c  = l & 15;
  int w  = nt / 12, tl = nt % 12;
  int gate = tl / 3, ti = tl % 3;
  int j = w * 48 + ti * 16 + c;
  float v = 0.f;
  if (j < D) {
    if (gate == 0) {
      if (k < D)        v = wih[j * D + k];
      else if (k < 2*D) v = whh[j * D + (k - D)];
    } else if (gate == 1) {
      if (k < D)        v = wih[(D + j) * D + k];
      else if (k < 2*D) v = whh[(D + j) * D + (k - D)];
    } else if (gate == 2) {
      if (k < D)        v = wih[(2*D + j) * D + k];
    } else {
      if (k >= D && k < 2*D) v = whh[(2*D + j) * D + (k - D)];
    }
  }
  Bpack[gid] = f2bf(v);
}

__global__ void mask_set_kernel(const int* __restrict__ ids, unsigned char* __restrict__ mask) {
  int i = blockIdx.x * 256 + threadIdx.x;
  if (i < N_UPD) mask[ids[i]] = 1;
}

// Full copy (fallback when ws too small for mask)
__global__ void copy_kernel(const float4* __restrict__ mem4, const float4* __restrict__ lu4,
                            float4* __restrict__ out4, float4* __restrict__ outlu4) {
  const long NL4 = N_NODES / 4;
  long stride = (long)gridDim.x * blockDim.x;
  for (long i = (long)blockIdx.x * blockDim.x + threadIdx.x; i < NM4 + NL4; i += stride) {
    if (i < NM4) out4[i] = mem4[i];
    else         outlu4[i - NM4] = lu4[i - NM4];
  }
}

// ---------------------------------------------------------------------------
// Fused kernel: cycles of 5 block-groups (8 blocks = XCD quantum):
// groups 0..2 -> GRU blocks, groups 3..4 -> masked-copy blocks.
// Disjoint writes via mask -> no ordering needed. Copy hides under gru.
// GRU path: r8-verified 8-wave ti-loop, 8 live accs, no K-loop barriers.
// ---------------------------------------------------------------------------
__global__ __launch_bounds__(512, 4)
void fused_kernel(const float* __restrict__ memory, const float* __restrict__ last_update,
                  const float* __restrict__ msgs, const int* __restrict__ ids,
                  const float* __restrict__ ts, const unsigned short* __restrict__ Bpack,
                  const float* __restrict__ bias4, const unsigned char* __restrict__ mask,
                  float* __restrict__ out_mem, float* __restrict__ out_lu, int has_copy) {
  __shared__ unsigned short At[BM * LDA];   // 46080 B
  const int tid = threadIdx.x;
  int idx;
  if (has_copy) {
    const int g8 = blockIdx.x >> 3, b7 = blockIdx.x & 7;
    const int cyc = g8 / 5, pos = g8 - cyc * 5;
    if (pos >= 3) {
      // ---- masked copy path ----
      const int cblk = (cyc * 2 + (pos - 3)) * 8 + b7;
      const float4* mem4 = (const float4*)memory;
      float4* out4 = (float4*)out_mem;
      for (unsigned i = (unsigned)cblk * 512 + tid; i < NM4; i += COPY_STRIDE) {
        unsigned row = i / 43u;
        if (!mask[row]) out4[i] = mem4[i];
      }
      for (unsigned j = (unsigned)cblk * 512 + tid; j < N_NODES; j += COPY_STRIDE) {
        if (!mask[j]) out_lu[j] = last_update[j];
      }
      return;
    }
    idx = (cyc * 3 + pos) * 8 + b7;
    if (idx >= GRU_BLOCKS) return;
  } else {
    idx = blockIdx.x;
  }

  // ---- GRU path ----
  const int m0   = idx * BM;
  const int wave = tid >> 6, lane = tid & 63;
  const int g = lane >> 4, c = lane & 15;
  const int wm = wave >> 2, wc = wave & 3;

  // A staging: 64 rows x (43 x-float4 + 43 h-float4) -> bf16 LDS
  const float4* x4 = (const float4*)msgs + (size_t)m0 * 43;
  float4 xv[6], hv[6];
  #pragma unroll
  for (int i = 0; i < 6; ++i) {
    int s = tid + i * 512;
    if (i < 5 || s < 2752) xv[i] = x4[s];
  }
  #pragma unroll
  for (int i = 0; i < 6; ++i) {
    int s = tid + i * 512;
    if (i < 5 || s < 2752) {
      int row = s / 43, seg = s - row * 43;
      hv[i] = ((const float4*)(memory + (size_t)ids[m0 + row] * D))[seg];
    }
  }
  #pragma unroll
  for (int i = 0; i < 6; ++i) {
    int s = tid + i * 512;
    if (i < 5 || s < 2752) {
      int row = s / 43, seg = s - row * 43;
      *(ushort4*)&At[row * LDA + seg * 4]       = f2bf4(xv[i]);
      *(ushort4*)&At[row * LDA + 172 + seg * 4] = f2bf4(hv[i]);
    }
  }
  if (tid < BM) {   // zero-pad k=344..351 (k=352..359 never read) + lu scatter
    *(uint4*)&At[tid * LDA + 344] = make_uint4(0, 0, 0, 0);
    out_lu[ids[m0 + tid]] = ts[m0 + tid];
  }
  __syncthreads();

  const int ar0 = (wm * 32 + c) * LDA;
  const int ar1 = ar0 + 16 * LDA;
  const short8* Bp = (const short8*)Bpack;

  #pragma unroll 1
  for (int ti = 0; ti < 3; ++ti) {
    if (wc == 3 && ti == 2) continue;   // j = 176..191: all padding
    const short8* bp = Bp + (size_t)((wc * 12 + ti) * 64 + lane);

    f32x4 Cr0={0,0,0,0}, Cr1={0,0,0,0};
    f32x4 Cz0={0,0,0,0}, Cz1={0,0,0,0};
    f32x4 Ci0={0,0,0,0}, Ci1={0,0,0,0};
    f32x4 Ch0={0,0,0,0}, Ch1={0,0,0,0};

    #pragma unroll 2
    for (int ks = 0; ks < KSTEPS; ++ks) {
      const short8* bk = bp + ks * 3072;
      short8 br = bk[0];
      short8 bz = bk[192];
      short8 bi = bk[384];
      short8 bh = bk[576];
      short8 a0 = *(const short8*)&At[ar0 + ks * 32 + g * 8];
      short8 a1 = *(const short8*)&At[ar1 + ks * 32 + g * 8];
      Cr0 = __builtin_amdgcn_mfma_f32_16x16x32_bf16(a0, br, Cr0, 0, 0, 0);
      Cr1 = __builtin_amdgcn_mfma_f32_16x16x32_bf16(a1, br, Cr1, 0, 0, 0);
      Cz0 = __builtin_amdgcn_mfma_f32_16x16x32_bf16(a0, bz, Cz0, 0, 0, 0);
      Cz1 = __builtin_amdgcn_mfma_f32_16x16x32_bf16(a1, bz, Cz1, 0, 0, 0);
      Ci0 = __builtin_amdgcn_mfma_f32_16x16x32_bf16(a0, bi, Ci0, 0, 0, 0);
      Ci1 = __builtin_amdgcn_mfma_f32_16x16x32_bf16(a1, bi, Ci1, 0, 0, 0);
      Ch0 = __builtin_amdgcn_mfma_f32_16x16x32_bf16(a0, bh, Ch0, 0, 0, 0);
      Ch1 = __builtin_amdgcn_mfma_f32_16x16x32_bf16(a1, bh, Ch1, 0, 0, 0);
    }

    const int j = wc * 48 + ti * 16 + c;
    if (j < D) {
      const float b_r = bias4[j];
      const float b_z = bias4[172 + j];
      const float b_i = bias4[344 + j];
      const float b_h = bias4[516 + j];
      #pragma unroll
      for (int r = 0; r < 4; ++r) {
        {
          const int row_local = wm * 32 + g * 4 + r;
          float* orow = out_mem + (size_t)ids[m0 + row_local] * D;
          float ho = bf2f(At[row_local * LDA + 172 + j]);
          float rr = 1.f / (1.f + __expf(-(Cr0[r] + b_r)));
          float zz = 1.f / (1.f + __expf(-(Cz0[r] + b_z)));
          float e2 = __expf(2.f * (Ci0[r] + b_i + rr * (Ch0[r] + b_h)));
          float nn = 1.f - 2.f / (e2 + 1.f);
          orow[j] = nn + zz * (ho - nn);
        }
        {
          const int row_local = wm * 32 + 16 + g * 4 + r;
          float* orow = out_mem + (size_t)ids[m0 + row_local] * D;
          float ho = bf2f(At[row_local * LDA + 172 + j]);
          float rr = 1.f / (1.f + __expf(-(Cr1[r] + b_r)));
          float zz = 1.f / (1.f + __expf(-(Cz1[r] + b_z)));
          float e2 = __expf(2.f * (Ci1[r] + b_i + rr * (Ch1[r] + b_h)));
          float nn = 1.f - 2.f / (e2 + 1.f);
          orow[j] = nn + zz * (ho - nn);
        }
      }
    }
  }
}

extern "C" void kernel_launch(void* const* d_in, const int* in_sizes, int n_in,
                              void* d_out, int out_size, void* d_ws, size_t ws_size,
                              hipStream_t stream) {
  const float* memory      = (const float*)d_in[0];
  const float* last_update = (const float*)d_in[1];
  const int*   ids         = (const int*)  d_in[2];
  const float* msgs        = (const float*)d_in[3];
  const float* ts          = (const float*)d_in[4];
  const float* wih         = (const float*)d_in[5];
  const float* whh         = (const float*)d_in[6];
  const float* bih         = (const float*)d_in[7];
  const float* bhh         = (const float*)d_in[8];

  float* out_mem = (float*)d_out;
  float* out_lu  = out_mem + (size_t)N_NODES * D;

  unsigned short* Bpack = (unsigned short*)d_ws;
  float* bias4 = (float*)((char*)d_ws + BIAS_OFF);
  unsigned char* mask = (unsigned char*)d_ws + MASK_OFF;

  prep_kernel<<<BPACK_USHORTS / 256, 256, 0, stream>>>(wih, whh, bih, bhh, Bpack, bias4,
                                                       (uint4*)mask);
  if (ws_size >= WS_NEED) {
    mask_set_kernel<<<(N_UPD + 255) / 256, 256, 0, stream>>>(ids, mask);
    fused_kernel<<<NCYC * 5 * 8, 512, 0, stream>>>(memory, last_update, msgs, ids, ts,
                                                   Bpack, bias4, mask, out_mem, out_lu, 1);
  } else {
    copy_kernel<<<4096, 256, 0, stream>>>((const float4*)memory, (const float4*)last_update,
                                          (float4*)out_mem, (float4*)out_lu);
    fused_kernel<<<GRU_BLOCKS, 512, 0, stream>>>(memory, last_update, msgs, ids, ts,
                                                 Bpack, bias4, mask, out_mem, out_lu, 0);
  }
}